// Round 10
// baseline (39.640 us; speedup 1.0000x reference)
//
#include <hip/hip_runtime.h>
#include <math.h>

// Geometry fixed by reference: B=4, C=3, D=H=W=64.
#define VOXB 262144              // 64^3
#define NVOX 1048576             // 4 * VOXB
#define NACC 11
#define PITCH 68                 // u32 pitch: mult-of-4 => aligned b128; %32=4 => even banks
#define NBLKB 256                // kernel B grid: 1 block per (b,d0) plane
#define CLAMP14 16383            // genuine 3D d^2 <= 3*63^2 = 11907 < 16383; packed u16
                                 // adds stay <= 20352+3969 < 65536 (no overflow)

// ---------------------------------------------------------------------------
// Packed u16 pair ops (VOP3P). pos distance^2 in lo16, neg in hi16.
// ---------------------------------------------------------------------------
__device__ __forceinline__ unsigned pk_min(unsigned a, unsigned b) {
    unsigned d; asm("v_pk_min_u16 %0, %1, %2" : "=v"(d) : "v"(a), "v"(b)); return d;
}
__device__ __forceinline__ unsigned pk_max(unsigned a, unsigned b) {
    unsigned d; asm("v_pk_max_u16 %0, %1, %2" : "=v"(d) : "v"(a), "v"(b)); return d;
}
__device__ __forceinline__ unsigned pk_add(unsigned a, unsigned b) {
    unsigned d; asm("v_pk_add_u16 %0, %1, %2" : "=v"(d) : "v"(a), "v"(b)); return d;
}

// Squared distance (int) from position i to nearest set bit of 64b mask.
// Empty mask -> clamped 16383 ("inf"; never beats a genuine candidate;
// all-empty/all-full volumes take the gsum branch in final assembly).
__device__ __forceinline__ unsigned n2i(unsigned long long m, int i) {
    unsigned long long right = m >> i;
    unsigned long long left  = m << (63 - i);
    int dr = right ? __builtin_ctzll(right) : 1000;
    int dl = left  ? __builtin_clzll(left)  : 1000;
    int d  = dr < dl ? dr : dl;
    int d2 = d * d;
    return (unsigned)(d2 > CLAMP14 ? CLAMP14 : d2);
}

// lgkm-only barrier: LDS ordering without draining outstanding global loads.
__device__ __forceinline__ void lgkm_barrier() {
    asm volatile("s_waitcnt lgkmcnt(0)" ::: "memory");
    __builtin_amdgcn_s_barrier();
    asm volatile("" ::: "memory");
}

// ---------------------------------------------------------------------------
// Kernel A: build 64-bit d-column masks. Block = (b,h) slab; wave wv owns
// d in [wv*8, wv*8+8); lane = w. Output Mask[b*4096 + h*64 + w] (128 KB).
// Block 0 also re-zeros the atomic accumulators + completion counter
// (kernel-end device release makes the zeros visible to B's atomics).
// ---------------------------------------------------------------------------
__global__ __launch_bounds__(512) void build_masks(
        const int* __restrict__ targets, unsigned long long* __restrict__ Mask,
        float* __restrict__ G, int* __restrict__ counter) {
    __shared__ unsigned long long Mp[8][64];
    int slab = blockIdx.x;               // b*64 + h
    int b = slab >> 6, h = slab & 63;
    int wv = threadIdx.x >> 6, lane = threadIdx.x & 63;
    if (blockIdx.x == 0) {
        if (threadIdx.x < 4 * NACC) G[threadIdx.x] = 0.f;
        if (threadIdx.x == 4 * NACC) *counter = 0;
    }
    int base = b * VOXB + h * 64 + lane;
    unsigned long long bits = 0;
#pragma unroll
    for (int rt = 0; rt < 8; ++rt) {
        int d = wv * 8 + rt;
        int tv = targets[base + d * 4096];
        bits |= ((unsigned long long)(tv == 1)) << d;
    }
    Mp[wv][lane] = bits;
    __syncthreads();
    if (wv == 0) {
        unsigned long long m = Mp[0][lane] | Mp[1][lane] | Mp[2][lane] |
                               Mp[3][lane] | Mp[4][lane] | Mp[5][lane] |
                               Mp[6][lane] | Mp[7][lane];
        Mask[slab * 64 + lane] = m;
    }
}

// ---------------------------------------------------------------------------
// Per-voxel pointwise math. 11 accumulators:
// 0 focal, 1..3 inter_c, 4 psum1, 5 psum2, 6 tsum1, 7 tsum2,
// 8 sknum, 9 skden, 10 term(p1*sd).   (psum0/tsum0 derived in assembly.)
// ---------------------------------------------------------------------------
__device__ __forceinline__ void vox_accum(float l0, float l1, float l2,
                                          int tg, int s, float sd, float* acc) {
    float m  = fmaxf(l0, fmaxf(l1, l2));
    float e0 = __expf(l0 - m), e1 = __expf(l1 - m), e2 = __expf(l2 - m);
    float sum = e0 + e1 + e2;
    float inv = 1.0f / sum;
    float p0 = e0 * inv, p1 = e1 * inv, p2 = e2 * inv;
    float logs = __logf(sum);
    float pt, lpt, alpha;
    if (tg == 0)      { pt = p0; lpt = l0 - m - logs; alpha = 0.3f; }
    else if (tg == 1) { pt = p1; lpt = l1 - m - logs; alpha = 3.0f; }
    else              { pt = p2; lpt = l2 - m - logs; alpha = 0.3f; }
    float om = 1.0f - pt;
    acc[0] += alpha * om * om * lpt;
    acc[1] += (tg == 0) ? p0 : 0.f;
    acc[2] += (tg == 1) ? p1 : 0.f;
    acc[3] += (tg == 2) ? p2 : 0.f;
    acc[4] += p1; acc[5] += p2;
    acc[6] += (tg == 1) ? 1.f : 0.f;
    acc[7] += (tg == 2) ? 1.f : 0.f;
    float fs = (float)s;
    acc[8] += p1 * fs;
    acc[9] += fs;
    acc[10] += p1 * sd;
}

// ---------------------------------------------------------------------------
// Kernel B: one 1024-thread block per (b,d0) plane. D-pass bit-scan; W/H
// spirals (R8 structure: b128 reads, per-iter early exit). Block sums go
// straight to 44 global accumulators via device-scope atomicAdd (coherent
// point => NO fences). Last block (ACQ_REL counter) assembles the final
// 4 scalars in f64. Kernel C eliminated.
// ---------------------------------------------------------------------------
__global__ __launch_bounds__(1024) void edt_reduce(
        const float* __restrict__ logits, const int* __restrict__ targets,
        const int* __restrict__ skel, const unsigned long long* __restrict__ Mask,
        float* __restrict__ G, int* __restrict__ counter,
        float* __restrict__ out) {
    __shared__ unsigned V0T[64 * PITCH];   // [w][h] packed D-dist (pos|neg<<16)
    __shared__ unsigned T2 [64 * PITCH];   // [h][w] packed W+D dist
    __shared__ float red[NACC * 1024];     // 44 KB
    __shared__ int lastFlag;
    __shared__ float sg[4 * NACC];
    int plane = blockIdx.x;                // b*64 + d0
    int b = plane >> 6, d0 = plane & 63;
    int t = threadIdx.x;
    int wv = t >> 6, lane = t & 63;
    int hbase = wv * 4, wbase = wv * 4;

    // --- issue all global loads up front (land during the spirals) ---------
    const unsigned long long* mb = Mask + b * 4096;
    unsigned long long mk[4];
#pragma unroll
    for (int rt = 0; rt < 4; ++rt) mk[rt] = mb[(hbase + rt) * 64 + lane];

    int pbase = b * VOXB + d0 * 4096 + lane * 64 + wbase;   // (h=lane, w=wbase)
    int4 tv4 = *reinterpret_cast<const int4*>(targets + pbase);
    int4 sv4 = *reinterpret_cast<const int4*>(skel + pbase);
    size_t lbase = (size_t)b * (3 * VOXB) + d0 * 4096 + lane * 64 + wbase;
    float4 L0 = *reinterpret_cast<const float4*>(logits + lbase);
    float4 L1 = *reinterpret_cast<const float4*>(logits + lbase + VOXB);
    float4 L2 = *reinterpret_cast<const float4*>(logits + lbase + 2 * VOXB);

    // --- D-pass: bit-scan, packed; write V0T[w=lane][hbase..+3] (b128) -----
    unsigned mp[4];
#pragma unroll
    for (int rt = 0; rt < 4; ++rt)
        mp[rt] = n2i(mk[rt], d0) | (n2i(~mk[rt], d0) << 16);
    *reinterpret_cast<uint4*>(&V0T[lane * PITCH + hbase]) =
        make_uint4(mp[0], mp[1], mp[2], mp[3]);

    // --- W-pass spiral (wave-local rows; per-iter uniform early exit) ------
    for (int r = 1; r < 64; ++r) {
        int jl = lane - r; jl = jl < 0 ? 0 : jl;
        int jr = lane + r; jr = jr > 63 ? 63 : jr;
        uint4 qa = *reinterpret_cast<const uint4*>(&V0T[jl * PITCH + hbase]);
        uint4 qc = *reinterpret_cast<const uint4*>(&V0T[jr * PITCH + hbase]);
        unsigned rr2 = (unsigned)(r * r) * 0x10001u;
        unsigned mx;
        mp[0] = pk_min(mp[0], pk_add(pk_min(qa.x, qc.x), rr2)); mx = mp[0];
        mp[1] = pk_min(mp[1], pk_add(pk_min(qa.y, qc.y), rr2)); mx = pk_max(mx, mp[1]);
        mp[2] = pk_min(mp[2], pk_add(pk_min(qa.z, qc.z), rr2)); mx = pk_max(mx, mp[2]);
        mp[3] = pk_min(mp[3], pk_add(pk_min(qa.w, qc.w), rr2)); mx = pk_max(mx, mp[3]);
        unsigned thr = (unsigned)((r + 1) * (r + 1));
        if (__all(((mx & 0xffffu) <= thr) && ((mx >> 16) <= thr))) break;
    }
    // write T2[h=hbase+rt][w=lane] (4 x b32, conflict-free)
#pragma unroll
    for (int rt = 0; rt < 4; ++rt) T2[(hbase + rt) * PITCH + lane] = mp[rt];
    lgkm_barrier();                        // T2 handoff (globals stay in flight)

    // --- H-pass spiral at NEW ownership (h=lane, w=wbase..+3) --------------
    uint4 q0 = *reinterpret_cast<const uint4*>(&T2[lane * PITCH + wbase]);
    unsigned mh[4] = {q0.x, q0.y, q0.z, q0.w};
    for (int r = 1; r < 64; ++r) {
        int jl = lane - r; jl = jl < 0 ? 0 : jl;
        int jr = lane + r; jr = jr > 63 ? 63 : jr;
        uint4 qa = *reinterpret_cast<const uint4*>(&T2[jl * PITCH + wbase]);
        uint4 qc = *reinterpret_cast<const uint4*>(&T2[jr * PITCH + wbase]);
        unsigned rr2 = (unsigned)(r * r) * 0x10001u;
        unsigned mx;
        mh[0] = pk_min(mh[0], pk_add(pk_min(qa.x, qc.x), rr2)); mx = mh[0];
        mh[1] = pk_min(mh[1], pk_add(pk_min(qa.y, qc.y), rr2)); mx = pk_max(mx, mh[1]);
        mh[2] = pk_min(mh[2], pk_add(pk_min(qa.z, qc.z), rr2)); mx = pk_max(mx, mh[2]);
        mh[3] = pk_min(mh[3], pk_add(pk_min(qa.w, qc.w), rr2)); mx = pk_max(mx, mh[3]);
        unsigned thr = (unsigned)((r + 1) * (r + 1));
        if (__all(((mx & 0xffffu) <= thr) && ((mx >> 16) <= thr))) break;
    }

    // --- pointwise (vector loads arrive here) + accumulate ------------------
    float acc[NACC];
#pragma unroll
    for (int k = 0; k < NACC; ++k) acc[k] = 0.f;
    {
        float sd0 = sqrtf((float)(mh[0] & 0xffffu)) - sqrtf((float)(mh[0] >> 16));
        float sd1 = sqrtf((float)(mh[1] & 0xffffu)) - sqrtf((float)(mh[1] >> 16));
        float sd2 = sqrtf((float)(mh[2] & 0xffffu)) - sqrtf((float)(mh[2] >> 16));
        float sd3 = sqrtf((float)(mh[3] & 0xffffu)) - sqrtf((float)(mh[3] >> 16));
        vox_accum(L0.x, L1.x, L2.x, tv4.x, sv4.x, sd0, acc);
        vox_accum(L0.y, L1.y, L2.y, tv4.y, sv4.y, sd1, acc);
        vox_accum(L0.z, L1.z, L2.z, tv4.z, sv4.z, sd2, acc);
        vox_accum(L0.w, L1.w, L2.w, tv4.w, sv4.w, sd3, acc);
    }

    // --- LDS-transpose reduction -> device-scope atomic accumulators --------
#pragma unroll
    for (int k = 0; k < NACC; ++k) red[k * 1024 + t] = acc[k];
    lgkm_barrier();
    if (wv < NACC) {                       // wave wv reduces accumulator wv
        const float* p = red + wv * 1024;
        float v = 0.f;
#pragma unroll
        for (int c = 0; c < 16; ++c) v += p[lane + c * 64];
#pragma unroll
        for (int off = 32; off; off >>= 1) v += __shfl_down(v, off, 64);
        if (lane == 0)
            __hip_atomic_fetch_add(&G[b * NACC + wv], v,
                                   __ATOMIC_RELAXED, __HIP_MEMORY_SCOPE_AGENT);
    }
    __syncthreads();                       // drains every wave's atomic (vmcnt)

    // --- last-block final assembly (no fences, no spin) ---------------------
    if (t == 0) {
        int prev = __hip_atomic_fetch_add(counter, 1, __ATOMIC_ACQ_REL,
                                          __HIP_MEMORY_SCOPE_AGENT);
        lastFlag = (prev == NBLKB - 1);
    }
    __syncthreads();
    if (lastFlag) {
        if (t < 4 * NACC)
            sg[t] = __hip_atomic_load(&G[t], __ATOMIC_ACQUIRE,
                                      __HIP_MEMORY_SCOPE_AGENT);
        __syncthreads();
        if (t == 0) {
            double S[NACC];
#pragma unroll
            for (int k = 0; k < NACC; ++k)
                S[k] = (double)sg[0 * NACC + k] + sg[1 * NACC + k] +
                       (double)sg[2 * NACC + k] + sg[3 * NACC + k];
            double psum0 = (double)NVOX - S[4] - S[5];
            double tsum0 = (double)NVOX - S[6] - S[7];   // exact (integer counts)
            double focal = -S[0] / (double)NVOX;
            double dice =
                0.3 * (1.0 - (2.0 * S[1] + 1.0) / (psum0 + tsum0 + 1.0)) +
                3.0 * (1.0 - (2.0 * S[2] + 1.0) / (S[4] + S[6] + 1.0)) +
                0.3 * (1.0 - (2.0 * S[3] + 1.0) / (S[5] + S[7] + 1.0));
            double lfd = focal + dice / 3.6;
            double lsk = 1.0 - (S[8] + 1.0) / (S[9] + 1.0);
            double lb = 0.0;
            for (int bb = 0; bb < 4; ++bb) {
                double gs = sg[bb * NACC + 6];   // per-batch count of targets==1
                double ps = sg[bb * NACC + 4];   // per-batch sum of p1
                double tm = sg[bb * NACC + 10];  // per-batch sum of p1*sd
                double per;
                if (gs == 0.0)               per = ps / (double)VOXB;
                else if (gs == (double)VOXB) per = 1.0 - ps / (double)VOXB;
                else                         per = tm / (double)VOXB;
                lb += per;
            }
            lb *= 0.25;
            double total = 0.3 * lfd + 0.3 * lsk + 0.2 * lb;
            out[0] = (float)total;
            out[1] = (float)lfd;
            out[2] = (float)lsk;
            out[3] = (float)lb;
        }
    }
}

// ---------------------------------------------------------------------------
extern "C" void kernel_launch(void* const* d_in, const int* in_sizes, int n_in,
                              void* d_out, int out_size, void* d_ws, size_t ws_size,
                              hipStream_t stream) {
    const float* logits  = (const float*)d_in[0];
    const int*   targets = (const int*)d_in[1];
    const int*   skel    = (const int*)d_in[2];
    unsigned long long* Mask = (unsigned long long*)d_ws;   // 16384 u64 (128 KB)
    float* G       = (float*)(Mask + 16384);                // 44 atomic sums
    int*   counter = (int*)(G + 4 * NACC);
    float* out = (float*)d_out;

    build_masks<<<256, 512, 0, stream>>>(targets, Mask, G, counter);
    edt_reduce<<<NBLKB, 1024, 0, stream>>>(logits, targets, skel, Mask,
                                           G, counter, out);
}

// Round 11
// 24.619 us; speedup vs baseline: 1.6102x; 1.6102x over previous
//
#include <hip/hip_runtime.h>
#include <math.h>

// Geometry fixed by reference: B=4, C=3, D=H=W=64.
#define VOXB 262144              // 64^3
#define NVOX 1048576             // 4 * VOXB
#define NACC 11
#define PITCH 68                 // u32 pitch: mult-of-4 => aligned b128; %32=4 => even banks
#define NBLKB 256                // kernel B grid: 1 block per (b,d0) plane
#define CLAMP14 16383            // genuine 3D d^2 <= 3*63^2 = 11907 < 16383; packed u16
                                 // adds stay <= 20352+3969 < 65536 (no overflow)

// ---------------------------------------------------------------------------
// Packed u16 pair ops (VOP3P). pos distance^2 in lo16, neg in hi16.
// ---------------------------------------------------------------------------
__device__ __forceinline__ unsigned pk_min(unsigned a, unsigned b) {
    unsigned d; asm("v_pk_min_u16 %0, %1, %2" : "=v"(d) : "v"(a), "v"(b)); return d;
}
__device__ __forceinline__ unsigned pk_max(unsigned a, unsigned b) {
    unsigned d; asm("v_pk_max_u16 %0, %1, %2" : "=v"(d) : "v"(a), "v"(b)); return d;
}
__device__ __forceinline__ unsigned pk_add(unsigned a, unsigned b) {
    unsigned d; asm("v_pk_add_u16 %0, %1, %2" : "=v"(d) : "v"(a), "v"(b)); return d;
}

// Squared distance (int) from position i to nearest set bit of 64b mask.
// Empty mask -> clamped 16383 ("inf"; never beats a genuine candidate;
// all-empty/all-full volumes take the gsum branch in final assembly).
__device__ __forceinline__ unsigned n2i(unsigned long long m, int i) {
    unsigned long long right = m >> i;
    unsigned long long left  = m << (63 - i);
    int dr = right ? __builtin_ctzll(right) : 1000;
    int dl = left  ? __builtin_clzll(left)  : 1000;
    int d  = dr < dl ? dr : dl;
    int d2 = d * d;
    return (unsigned)(d2 > CLAMP14 ? CLAMP14 : d2);
}

// lgkm-only barrier: LDS ordering without draining outstanding global loads.
__device__ __forceinline__ void lgkm_barrier() {
    asm volatile("s_waitcnt lgkmcnt(0)" ::: "memory");
    __builtin_amdgcn_s_barrier();
    asm volatile("" ::: "memory");
}

// ---------------------------------------------------------------------------
// Kernel A: build 64-bit d-column masks AND the packed per-voxel byte
// pk = t | s<<2 (so kernel B never touches targets/skel: 8 MB -> 1 MB).
// Block = (b,h) slab; wave wv owns d in [wv*8, wv*8+8); lane = w.
// All loads/stores coalesced (lane-contiguous).
// ---------------------------------------------------------------------------
__global__ __launch_bounds__(512) void build_masks(
        const int* __restrict__ targets, const int* __restrict__ skel,
        unsigned long long* __restrict__ Mask, unsigned char* __restrict__ pk) {
    __shared__ unsigned long long Mp[8][64];
    int slab = blockIdx.x;               // b*64 + h
    int b = slab >> 6, h = slab & 63;
    int wv = threadIdx.x >> 6, lane = threadIdx.x & 63;
    int base = b * VOXB + h * 64 + lane;
    unsigned long long bits = 0;
#pragma unroll
    for (int rt = 0; rt < 8; ++rt) {
        int d = wv * 8 + rt;
        int off = base + d * 4096;
        int tv = targets[off];
        int sv = skel[off];
        bits |= ((unsigned long long)(tv == 1)) << d;
        pk[off] = (unsigned char)(tv | (sv << 2));
    }
    Mp[wv][lane] = bits;
    __syncthreads();
    if (wv == 0) {
        unsigned long long m = Mp[0][lane] | Mp[1][lane] | Mp[2][lane] |
                               Mp[3][lane] | Mp[4][lane] | Mp[5][lane] |
                               Mp[6][lane] | Mp[7][lane];
        Mask[slab * 64 + lane] = m;
    }
}

// ---------------------------------------------------------------------------
// Per-voxel pointwise math. 11 accumulators:
// 0 focal, 1..3 inter_c, 4 psum1, 5 psum2, 6 tsum1, 7 tsum2,
// 8 sknum, 9 skden, 10 term(p1*sd).   (psum0/tsum0 derived in C.)
// ---------------------------------------------------------------------------
__device__ __forceinline__ void vox_accum(float l0, float l1, float l2,
                                          int tg, int s, float sd, float* acc) {
    float m  = fmaxf(l0, fmaxf(l1, l2));
    float e0 = __expf(l0 - m), e1 = __expf(l1 - m), e2 = __expf(l2 - m);
    float sum = e0 + e1 + e2;
    float inv = 1.0f / sum;
    float p0 = e0 * inv, p1 = e1 * inv, p2 = e2 * inv;
    float logs = __logf(sum);
    float pt, lpt, alpha;
    if (tg == 0)      { pt = p0; lpt = l0 - m - logs; alpha = 0.3f; }
    else if (tg == 1) { pt = p1; lpt = l1 - m - logs; alpha = 3.0f; }
    else              { pt = p2; lpt = l2 - m - logs; alpha = 0.3f; }
    float om = 1.0f - pt;
    acc[0] += alpha * om * om * lpt;
    acc[1] += (tg == 0) ? p0 : 0.f;
    acc[2] += (tg == 1) ? p1 : 0.f;
    acc[3] += (tg == 2) ? p2 : 0.f;
    acc[4] += p1; acc[5] += p2;
    acc[6] += (tg == 1) ? 1.f : 0.f;
    acc[7] += (tg == 2) ? 1.f : 0.f;
    float fs = (float)s;
    acc[8] += p1 * fs;
    acc[9] += fs;
    acc[10] += p1 * sd;
}

// ---------------------------------------------------------------------------
// Kernel B (R8 structure, proven best): one 1024-thread block per (b,d0)
// plane. D-pass bit-scan; W/H spirals (b128 reads, per-iter uniform early
// exit); fused pointwise (pk byte carries t,s); LDS-transpose reduction to
// block partials. No fences, no atomics.
// ---------------------------------------------------------------------------
__global__ __launch_bounds__(1024) void edt_reduce(
        const float* __restrict__ logits, const unsigned char* __restrict__ pk,
        const unsigned long long* __restrict__ Mask, float* __restrict__ partials) {
    __shared__ unsigned V0T[64 * PITCH];   // [w][h] packed D-dist (pos|neg<<16)
    __shared__ unsigned T2 [64 * PITCH];   // [h][w] packed W+D dist
    __shared__ float red[NACC * 1024];     // 44 KB
    int plane = blockIdx.x;                // b*64 + d0
    int b = plane >> 6, d0 = plane & 63;
    int t = threadIdx.x;
    int wv = t >> 6, lane = t & 63;
    int hbase = wv * 4, wbase = wv * 4;

    // --- issue all global loads up front (land during the spirals) ---------
    const unsigned long long* mb = Mask + b * 4096;
    unsigned long long mk[4];
#pragma unroll
    for (int rt = 0; rt < 4; ++rt) mk[rt] = mb[(hbase + rt) * 64 + lane];

    int pbase = b * VOXB + d0 * 4096 + lane * 64 + wbase;   // (h=lane, w=wbase)
    unsigned pk4 = *reinterpret_cast<const unsigned*>(pk + pbase);  // 4 voxels
    size_t lbase = (size_t)b * (3 * VOXB) + d0 * 4096 + lane * 64 + wbase;
    float4 L0 = *reinterpret_cast<const float4*>(logits + lbase);
    float4 L1 = *reinterpret_cast<const float4*>(logits + lbase + VOXB);
    float4 L2 = *reinterpret_cast<const float4*>(logits + lbase + 2 * VOXB);

    // --- D-pass: bit-scan, packed; write V0T[w=lane][hbase..+3] (b128) -----
    unsigned mp[4];
#pragma unroll
    for (int rt = 0; rt < 4; ++rt)
        mp[rt] = n2i(mk[rt], d0) | (n2i(~mk[rt], d0) << 16);
    *reinterpret_cast<uint4*>(&V0T[lane * PITCH + hbase]) =
        make_uint4(mp[0], mp[1], mp[2], mp[3]);

    // --- W-pass spiral (wave-local rows; per-iter uniform early exit) ------
    for (int r = 1; r < 64; ++r) {
        int jl = lane - r; jl = jl < 0 ? 0 : jl;
        int jr = lane + r; jr = jr > 63 ? 63 : jr;
        uint4 qa = *reinterpret_cast<const uint4*>(&V0T[jl * PITCH + hbase]);
        uint4 qc = *reinterpret_cast<const uint4*>(&V0T[jr * PITCH + hbase]);
        unsigned rr2 = (unsigned)(r * r) * 0x10001u;
        unsigned mx;
        mp[0] = pk_min(mp[0], pk_add(pk_min(qa.x, qc.x), rr2)); mx = mp[0];
        mp[1] = pk_min(mp[1], pk_add(pk_min(qa.y, qc.y), rr2)); mx = pk_max(mx, mp[1]);
        mp[2] = pk_min(mp[2], pk_add(pk_min(qa.z, qc.z), rr2)); mx = pk_max(mx, mp[2]);
        mp[3] = pk_min(mp[3], pk_add(pk_min(qa.w, qc.w), rr2)); mx = pk_max(mx, mp[3]);
        unsigned thr = (unsigned)((r + 1) * (r + 1));
        if (__all(((mx & 0xffffu) <= thr) && ((mx >> 16) <= thr))) break;
    }
    // write T2[h=hbase+rt][w=lane] (4 x b32, conflict-free)
#pragma unroll
    for (int rt = 0; rt < 4; ++rt) T2[(hbase + rt) * PITCH + lane] = mp[rt];
    lgkm_barrier();                        // T2 handoff (globals stay in flight)

    // --- H-pass spiral at NEW ownership (h=lane, w=wbase..+3) --------------
    uint4 q0 = *reinterpret_cast<const uint4*>(&T2[lane * PITCH + wbase]);
    unsigned mh[4] = {q0.x, q0.y, q0.z, q0.w};
    for (int r = 1; r < 64; ++r) {
        int jl = lane - r; jl = jl < 0 ? 0 : jl;
        int jr = lane + r; jr = jr > 63 ? 63 : jr;
        uint4 qa = *reinterpret_cast<const uint4*>(&T2[jl * PITCH + wbase]);
        uint4 qc = *reinterpret_cast<const uint4*>(&T2[jr * PITCH + wbase]);
        unsigned rr2 = (unsigned)(r * r) * 0x10001u;
        unsigned mx;
        mh[0] = pk_min(mh[0], pk_add(pk_min(qa.x, qc.x), rr2)); mx = mh[0];
        mh[1] = pk_min(mh[1], pk_add(pk_min(qa.y, qc.y), rr2)); mx = pk_max(mx, mh[1]);
        mh[2] = pk_min(mh[2], pk_add(pk_min(qa.z, qc.z), rr2)); mx = pk_max(mx, mh[2]);
        mh[3] = pk_min(mh[3], pk_add(pk_min(qa.w, qc.w), rr2)); mx = pk_max(mx, mh[3]);
        unsigned thr = (unsigned)((r + 1) * (r + 1));
        if (__all(((mx & 0xffffu) <= thr) && ((mx >> 16) <= thr))) break;
    }

    // --- pointwise (vector loads arrive here) + accumulate ------------------
    float acc[NACC];
#pragma unroll
    for (int k = 0; k < NACC; ++k) acc[k] = 0.f;
    {
        float sd0 = sqrtf((float)(mh[0] & 0xffffu)) - sqrtf((float)(mh[0] >> 16));
        float sd1 = sqrtf((float)(mh[1] & 0xffffu)) - sqrtf((float)(mh[1] >> 16));
        float sd2 = sqrtf((float)(mh[2] & 0xffffu)) - sqrtf((float)(mh[2] >> 16));
        float sd3 = sqrtf((float)(mh[3] & 0xffffu)) - sqrtf((float)(mh[3] >> 16));
        vox_accum(L0.x, L1.x, L2.x, (int)(pk4 & 3u), (int)((pk4 >> 2) & 1u), sd0, acc);
        vox_accum(L0.y, L1.y, L2.y, (int)((pk4 >> 8) & 3u), (int)((pk4 >> 10) & 1u), sd1, acc);
        vox_accum(L0.z, L1.z, L2.z, (int)((pk4 >> 16) & 3u), (int)((pk4 >> 18) & 1u), sd2, acc);
        vox_accum(L0.w, L1.w, L2.w, (int)((pk4 >> 24) & 3u), (int)((pk4 >> 26) & 1u), sd3, acc);
    }

    // --- LDS-transpose reduction -> block partials --------------------------
#pragma unroll
    for (int k = 0; k < NACC; ++k) red[k * 1024 + t] = acc[k];
    lgkm_barrier();
    if (wv < NACC) {                       // wave wv reduces accumulator wv
        const float* p = red + wv * 1024;
        float v = 0.f;
#pragma unroll
        for (int c = 0; c < 16; ++c) v += p[lane + c * 64];
#pragma unroll
        for (int off = 32; off; off >>= 1) v += __shfl_down(v, off, 64);
        if (lane == 0) partials[wv * NBLKB + blockIdx.x] = v;
    }
}

// ---------------------------------------------------------------------------
// Kernel C: final reduction (1 block, 256 threads). Batch b owns blocks
// [b*64, b*64+64); wave w reduces batch w. Thread 0 assembles in f64.
// ---------------------------------------------------------------------------
__global__ __launch_bounds__(256) void final_reduce(
        const float* __restrict__ partials, float* __restrict__ out) {
    __shared__ float sb[NACC][4];
    int w = threadIdx.x >> 6, lane = threadIdx.x & 63;
#pragma unroll
    for (int k = 0; k < NACC; ++k) {
        float v = partials[k * NBLKB + w * 64 + lane];
#pragma unroll
        for (int off = 32; off; off >>= 1) v += __shfl_down(v, off, 64);
        if (lane == 0) sb[k][w] = v;
    }
    __syncthreads();
    if (threadIdx.x == 0) {
        double S[NACC];
#pragma unroll
        for (int k = 0; k < NACC; ++k)
            S[k] = (double)sb[k][0] + sb[k][1] + sb[k][2] + sb[k][3];
        double psum0 = (double)NVOX - S[4] - S[5];
        double tsum0 = (double)NVOX - S[6] - S[7];   // exact (integer counts)
        double focal = -S[0] / (double)NVOX;
        double dice =
            0.3 * (1.0 - (2.0 * S[1] + 1.0) / (psum0 + tsum0 + 1.0)) +
            3.0 * (1.0 - (2.0 * S[2] + 1.0) / (S[4] + S[6] + 1.0)) +
            0.3 * (1.0 - (2.0 * S[3] + 1.0) / (S[5] + S[7] + 1.0));
        double lfd = focal + dice / 3.6;
        double lsk = 1.0 - (S[8] + 1.0) / (S[9] + 1.0);
        double lb = 0.0;
        for (int bb = 0; bb < 4; ++bb) {
            double gs = sb[6][bb];          // per-batch count of targets==1
            double ps = sb[4][bb];          // per-batch sum of p1
            double tm = sb[10][bb];         // per-batch sum of p1*sd
            double per;
            if (gs == 0.0)               per = ps / (double)VOXB;
            else if (gs == (double)VOXB) per = 1.0 - ps / (double)VOXB;
            else                         per = tm / (double)VOXB;
            lb += per;
        }
        lb *= 0.25;
        double total = 0.3 * lfd + 0.3 * lsk + 0.2 * lb;
        out[0] = (float)total;
        out[1] = (float)lfd;
        out[2] = (float)lsk;
        out[3] = (float)lb;
    }
}

// ---------------------------------------------------------------------------
extern "C" void kernel_launch(void* const* d_in, const int* in_sizes, int n_in,
                              void* d_out, int out_size, void* d_ws, size_t ws_size,
                              hipStream_t stream) {
    const float* logits  = (const float*)d_in[0];
    const int*   targets = (const int*)d_in[1];
    const int*   skel    = (const int*)d_in[2];
    unsigned long long* Mask = (unsigned long long*)d_ws;   // 16384 u64 (128 KB)
    float* partials = (float*)(Mask + 16384);               // NACC*NBLKB floats
    unsigned char* pkbuf = (unsigned char*)(partials + NACC * NBLKB); // 1 MB
    float* out = (float*)d_out;

    build_masks<<<256, 512, 0, stream>>>(targets, skel, Mask, pkbuf);
    edt_reduce<<<NBLKB, 1024, 0, stream>>>(logits, pkbuf, Mask, partials);
    final_reduce<<<1, 256, 0, stream>>>(partials, out);
}

// Round 12
// 23.789 us; speedup vs baseline: 1.6664x; 1.0349x over previous
//
#include <hip/hip_runtime.h>
#include <math.h>

// Geometry fixed by reference: B=4, C=3, D=H=W=64.
#define VOXB 262144              // 64^3
#define NVOX 1048576             // 4 * VOXB
#define NACC 11
#define NBLKB 256                // kernel B grid: 1 block per (b,d0) plane
#define CLAMP14 16383            // genuine 3D d^2 <= 3*63^2 = 11907 < 16383; packed u16
                                 // adds stay <= 20352+3969 < 65536 (no overflow)

// ---------------------------------------------------------------------------
// Swizzled 64x64 u32 tile: row pitch 64, 16B-group XOR swizzle.
// u32 index of the 16B group (c4 in [0,16)) of row: perfect bank spread for
// per-lane-row b128 access (16 consecutive lanes -> 16 distinct groups).
// ---------------------------------------------------------------------------
__device__ __forceinline__ int swz4(int row, int c4) {
    return row * 64 + (((c4) ^ (row & 15)) << 2);
}
__device__ __forceinline__ int swz1(int row, int col) {
    return row * 64 + ((((col >> 2) ^ (row & 15)) << 2) | (col & 3));
}

// ---------------------------------------------------------------------------
// Packed u16 pair ops (VOP3P). pos distance^2 in lo16, neg in hi16.
// ---------------------------------------------------------------------------
__device__ __forceinline__ unsigned pk_min(unsigned a, unsigned b) {
    unsigned d; asm("v_pk_min_u16 %0, %1, %2" : "=v"(d) : "v"(a), "v"(b)); return d;
}
__device__ __forceinline__ unsigned pk_max(unsigned a, unsigned b) {
    unsigned d; asm("v_pk_max_u16 %0, %1, %2" : "=v"(d) : "v"(a), "v"(b)); return d;
}
__device__ __forceinline__ unsigned pk_add(unsigned a, unsigned b) {
    unsigned d; asm("v_pk_add_u16 %0, %1, %2" : "=v"(d) : "v"(a), "v"(b)); return d;
}

// Squared distance (int) from position i to nearest set bit of 64b mask.
// Empty mask -> clamped 16383 ("inf"; never beats a genuine candidate;
// all-empty/all-full volumes take the gsum branch in final assembly).
__device__ __forceinline__ unsigned n2i(unsigned long long m, int i) {
    unsigned long long right = m >> i;
    unsigned long long left  = m << (63 - i);
    int dr = right ? __builtin_ctzll(right) : 1000;
    int dl = left  ? __builtin_clzll(left)  : 1000;
    int d  = dr < dl ? dr : dl;
    int d2 = d * d;
    return (unsigned)(d2 > CLAMP14 ? CLAMP14 : d2);
}

// lgkm-only barrier: LDS ordering without draining outstanding global loads.
__device__ __forceinline__ void lgkm_barrier() {
    asm volatile("s_waitcnt lgkmcnt(0)" ::: "memory");
    __builtin_amdgcn_s_barrier();
    asm volatile("" ::: "memory");
}

// ---------------------------------------------------------------------------
// Kernel A: build 64-bit d-column masks AND the packed per-voxel byte
// pk = t | s<<2 (kernel B never touches targets/skel). Block = (b,h) slab;
// wave wv owns d in [wv*8, wv*8+8); lane = w.
// ---------------------------------------------------------------------------
__global__ __launch_bounds__(512) void build_masks(
        const int* __restrict__ targets, const int* __restrict__ skel,
        unsigned long long* __restrict__ Mask, unsigned char* __restrict__ pk) {
    __shared__ unsigned long long Mp[8][64];
    int slab = blockIdx.x;               // b*64 + h
    int b = slab >> 6, h = slab & 63;
    int wv = threadIdx.x >> 6, lane = threadIdx.x & 63;
    int base = b * VOXB + h * 64 + lane;
    unsigned long long bits = 0;
#pragma unroll
    for (int rt = 0; rt < 8; ++rt) {
        int d = wv * 8 + rt;
        int off = base + d * 4096;
        int tv = targets[off];
        int sv = skel[off];
        bits |= ((unsigned long long)(tv == 1)) << d;
        pk[off] = (unsigned char)(tv | (sv << 2));
    }
    Mp[wv][lane] = bits;
    __syncthreads();
    if (wv == 0) {
        unsigned long long m = Mp[0][lane] | Mp[1][lane] | Mp[2][lane] |
                               Mp[3][lane] | Mp[4][lane] | Mp[5][lane] |
                               Mp[6][lane] | Mp[7][lane];
        Mask[slab * 64 + lane] = m;
    }
}

// ---------------------------------------------------------------------------
// Per-voxel pointwise math. 11 accumulators:
// 0 focal, 1..3 inter_c, 4 psum1, 5 psum2, 6 tsum1, 7 tsum2,
// 8 sknum, 9 skden, 10 term(p1*sd).   (psum0/tsum0 derived in C.)
// ---------------------------------------------------------------------------
__device__ __forceinline__ void vox_accum(float l0, float l1, float l2,
                                          int tg, int s, float sd, float* acc) {
    float m  = fmaxf(l0, fmaxf(l1, l2));
    float e0 = __expf(l0 - m), e1 = __expf(l1 - m), e2 = __expf(l2 - m);
    float sum = e0 + e1 + e2;
    float inv = 1.0f / sum;
    float p0 = e0 * inv, p1 = e1 * inv, p2 = e2 * inv;
    float logs = __logf(sum);
    float pt, lpt, alpha;
    if (tg == 0)      { pt = p0; lpt = l0 - m - logs; alpha = 0.3f; }
    else if (tg == 1) { pt = p1; lpt = l1 - m - logs; alpha = 3.0f; }
    else              { pt = p2; lpt = l2 - m - logs; alpha = 0.3f; }
    float om = 1.0f - pt;
    acc[0] += alpha * om * om * lpt;
    acc[1] += (tg == 0) ? p0 : 0.f;
    acc[2] += (tg == 1) ? p1 : 0.f;
    acc[3] += (tg == 2) ? p2 : 0.f;
    acc[4] += p1; acc[5] += p2;
    acc[6] += (tg == 1) ? 1.f : 0.f;
    acc[7] += (tg == 2) ? 1.f : 0.f;
    float fs = (float)s;
    acc[8] += p1 * fs;
    acc[9] += fs;
    acc[10] += p1 * sd;
}

// ---------------------------------------------------------------------------
// Kernel B: one 1024-thread block per (b,d0) plane. Same structure as R8/R11
// but with XOR-SWIZZLED LDS tiles (fixes the 8-way bank conflict of the
// constant-pitch layout: per-lane-row b128 reads now hit distinct banks).
// ---------------------------------------------------------------------------
__global__ __launch_bounds__(1024) void edt_reduce(
        const float* __restrict__ logits, const unsigned char* __restrict__ pk,
        const unsigned long long* __restrict__ Mask, float* __restrict__ partials) {
    __shared__ unsigned V0T[64 * 64];      // swizzled [w][h] packed D-dist
    __shared__ unsigned T2 [64 * 64];      // swizzled [h][w] packed W+D dist
    __shared__ float red[NACC * 1024];     // 44 KB
    int plane = blockIdx.x;                // b*64 + d0
    int b = plane >> 6, d0 = plane & 63;
    int t = threadIdx.x;
    int wv = t >> 6, lane = t & 63;
    int hbase = wv * 4, wbase = wv * 4;    // c4 = wv for both passes

    // --- issue all global loads up front (land during the spirals) ---------
    const unsigned long long* mb = Mask + b * 4096;
    unsigned long long mk[4];
#pragma unroll
    for (int rt = 0; rt < 4; ++rt) mk[rt] = mb[(hbase + rt) * 64 + lane];

    int pbase = b * VOXB + d0 * 4096 + lane * 64 + wbase;   // (h=lane, w=wbase)
    unsigned pk4 = *reinterpret_cast<const unsigned*>(pk + pbase);  // 4 voxels
    size_t lbase = (size_t)b * (3 * VOXB) + d0 * 4096 + lane * 64 + wbase;
    float4 L0 = *reinterpret_cast<const float4*>(logits + lbase);
    float4 L1 = *reinterpret_cast<const float4*>(logits + lbase + VOXB);
    float4 L2 = *reinterpret_cast<const float4*>(logits + lbase + 2 * VOXB);

    // --- D-pass: bit-scan, packed; write V0T row=lane, group=wv (b128) -----
    unsigned mp[4];
#pragma unroll
    for (int rt = 0; rt < 4; ++rt)
        mp[rt] = n2i(mk[rt], d0) | (n2i(~mk[rt], d0) << 16);
    *reinterpret_cast<uint4*>(&V0T[swz4(lane, wv)]) =
        make_uint4(mp[0], mp[1], mp[2], mp[3]);

    // --- W-pass spiral (wave-local rows; per-iter uniform early exit) ------
    for (int r = 1; r < 64; ++r) {
        int jl = lane - r; jl = jl < 0 ? 0 : jl;
        int jr = lane + r; jr = jr > 63 ? 63 : jr;
        uint4 qa = *reinterpret_cast<const uint4*>(&V0T[swz4(jl, wv)]);
        uint4 qc = *reinterpret_cast<const uint4*>(&V0T[swz4(jr, wv)]);
        unsigned rr2 = (unsigned)(r * r) * 0x10001u;
        unsigned mx;
        mp[0] = pk_min(mp[0], pk_add(pk_min(qa.x, qc.x), rr2)); mx = mp[0];
        mp[1] = pk_min(mp[1], pk_add(pk_min(qa.y, qc.y), rr2)); mx = pk_max(mx, mp[1]);
        mp[2] = pk_min(mp[2], pk_add(pk_min(qa.z, qc.z), rr2)); mx = pk_max(mx, mp[2]);
        mp[3] = pk_min(mp[3], pk_add(pk_min(qa.w, qc.w), rr2)); mx = pk_max(mx, mp[3]);
        unsigned thr = (unsigned)((r + 1) * (r + 1));
        if (__all(((mx & 0xffffu) <= thr) && ((mx >> 16) <= thr))) break;
    }
    // write T2 row=hbase+rt, col=lane (b32; bijective within row => 2-way max)
#pragma unroll
    for (int rt = 0; rt < 4; ++rt) T2[swz1(hbase + rt, lane)] = mp[rt];
    lgkm_barrier();                        // T2 handoff (globals stay in flight)

    // --- H-pass spiral at NEW ownership (h=lane, w=wbase..+3) --------------
    uint4 q0 = *reinterpret_cast<const uint4*>(&T2[swz4(lane, wv)]);
    unsigned mh[4] = {q0.x, q0.y, q0.z, q0.w};
    for (int r = 1; r < 64; ++r) {
        int jl = lane - r; jl = jl < 0 ? 0 : jl;
        int jr = lane + r; jr = jr > 63 ? 63 : jr;
        uint4 qa = *reinterpret_cast<const uint4*>(&T2[swz4(jl, wv)]);
        uint4 qc = *reinterpret_cast<const uint4*>(&T2[swz4(jr, wv)]);
        unsigned rr2 = (unsigned)(r * r) * 0x10001u;
        unsigned mx;
        mh[0] = pk_min(mh[0], pk_add(pk_min(qa.x, qc.x), rr2)); mx = mh[0];
        mh[1] = pk_min(mh[1], pk_add(pk_min(qa.y, qc.y), rr2)); mx = pk_max(mx, mh[1]);
        mh[2] = pk_min(mh[2], pk_add(pk_min(qa.z, qc.z), rr2)); mx = pk_max(mx, mh[2]);
        mh[3] = pk_min(mh[3], pk_add(pk_min(qa.w, qc.w), rr2)); mx = pk_max(mx, mh[3]);
        unsigned thr = (unsigned)((r + 1) * (r + 1));
        if (__all(((mx & 0xffffu) <= thr) && ((mx >> 16) <= thr))) break;
    }

    // --- pointwise (vector loads arrive here) + accumulate ------------------
    float acc[NACC];
#pragma unroll
    for (int k = 0; k < NACC; ++k) acc[k] = 0.f;
    {
        float sd0 = sqrtf((float)(mh[0] & 0xffffu)) - sqrtf((float)(mh[0] >> 16));
        float sd1 = sqrtf((float)(mh[1] & 0xffffu)) - sqrtf((float)(mh[1] >> 16));
        float sd2 = sqrtf((float)(mh[2] & 0xffffu)) - sqrtf((float)(mh[2] >> 16));
        float sd3 = sqrtf((float)(mh[3] & 0xffffu)) - sqrtf((float)(mh[3] >> 16));
        vox_accum(L0.x, L1.x, L2.x, (int)(pk4 & 3u), (int)((pk4 >> 2) & 1u), sd0, acc);
        vox_accum(L0.y, L1.y, L2.y, (int)((pk4 >> 8) & 3u), (int)((pk4 >> 10) & 1u), sd1, acc);
        vox_accum(L0.z, L1.z, L2.z, (int)((pk4 >> 16) & 3u), (int)((pk4 >> 18) & 1u), sd2, acc);
        vox_accum(L0.w, L1.w, L2.w, (int)((pk4 >> 24) & 3u), (int)((pk4 >> 26) & 1u), sd3, acc);
    }

    // --- LDS-transpose reduction -> block partials --------------------------
#pragma unroll
    for (int k = 0; k < NACC; ++k) red[k * 1024 + t] = acc[k];
    lgkm_barrier();
    if (wv < NACC) {                       // wave wv reduces accumulator wv
        const float* p = red + wv * 1024;
        float v = 0.f;
#pragma unroll
        for (int c = 0; c < 16; ++c) v += p[lane + c * 64];
#pragma unroll
        for (int off = 32; off; off >>= 1) v += __shfl_down(v, off, 64);
        if (lane == 0) partials[wv * NBLKB + blockIdx.x] = v;
    }
}

// ---------------------------------------------------------------------------
// Kernel C: final reduction (1 block, 256 threads). Batch b owns blocks
// [b*64, b*64+64); wave w reduces batch w. Thread 0 assembles in f64.
// ---------------------------------------------------------------------------
__global__ __launch_bounds__(256) void final_reduce(
        const float* __restrict__ partials, float* __restrict__ out) {
    __shared__ float sb[NACC][4];
    int w = threadIdx.x >> 6, lane = threadIdx.x & 63;
#pragma unroll
    for (int k = 0; k < NACC; ++k) {
        float v = partials[k * NBLKB + w * 64 + lane];
#pragma unroll
        for (int off = 32; off; off >>= 1) v += __shfl_down(v, off, 64);
        if (lane == 0) sb[k][w] = v;
    }
    __syncthreads();
    if (threadIdx.x == 0) {
        double S[NACC];
#pragma unroll
        for (int k = 0; k < NACC; ++k)
            S[k] = (double)sb[k][0] + sb[k][1] + sb[k][2] + sb[k][3];
        double psum0 = (double)NVOX - S[4] - S[5];
        double tsum0 = (double)NVOX - S[6] - S[7];   // exact (integer counts)
        double focal = -S[0] / (double)NVOX;
        double dice =
            0.3 * (1.0 - (2.0 * S[1] + 1.0) / (psum0 + tsum0 + 1.0)) +
            3.0 * (1.0 - (2.0 * S[2] + 1.0) / (S[4] + S[6] + 1.0)) +
            0.3 * (1.0 - (2.0 * S[3] + 1.0) / (S[5] + S[7] + 1.0));
        double lfd = focal + dice / 3.6;
        double lsk = 1.0 - (S[8] + 1.0) / (S[9] + 1.0);
        double lb = 0.0;
        for (int bb = 0; bb < 4; ++bb) {
            double gs = sb[6][bb];          // per-batch count of targets==1
            double ps = sb[4][bb];          // per-batch sum of p1
            double tm = sb[10][bb];         // per-batch sum of p1*sd
            double per;
            if (gs == 0.0)               per = ps / (double)VOXB;
            else if (gs == (double)VOXB) per = 1.0 - ps / (double)VOXB;
            else                         per = tm / (double)VOXB;
            lb += per;
        }
        lb *= 0.25;
        double total = 0.3 * lfd + 0.3 * lsk + 0.2 * lb;
        out[0] = (float)total;
        out[1] = (float)lfd;
        out[2] = (float)lsk;
        out[3] = (float)lb;
    }
}

// ---------------------------------------------------------------------------
extern "C" void kernel_launch(void* const* d_in, const int* in_sizes, int n_in,
                              void* d_out, int out_size, void* d_ws, size_t ws_size,
                              hipStream_t stream) {
    const float* logits  = (const float*)d_in[0];
    const int*   targets = (const int*)d_in[1];
    const int*   skel    = (const int*)d_in[2];
    unsigned long long* Mask = (unsigned long long*)d_ws;   // 16384 u64 (128 KB)
    float* partials = (float*)(Mask + 16384);               // NACC*NBLKB floats
    unsigned char* pkbuf = (unsigned char*)(partials + NACC * NBLKB); // 1 MB
    float* out = (float*)d_out;

    build_masks<<<256, 512, 0, stream>>>(targets, skel, Mask, pkbuf);
    edt_reduce<<<NBLKB, 1024, 0, stream>>>(logits, pkbuf, Mask, partials);
    final_reduce<<<1, 256, 0, stream>>>(partials, out);
}